// Round 1
// baseline (196.634 us; speedup 1.0000x reference)
//
#include <hip/hip_runtime.h>

#define DEV __device__ __forceinline__

typedef __attribute__((ext_vector_type(4))) float  f32x4;
typedef __attribute__((ext_vector_type(8))) short  short8v;
typedef __attribute__((ext_vector_type(4))) short  short4v;

// Problem sizes (fixed by the reference)
static constexpr int Bq = 2, Lq = 512, Dq = 512, Pq = 64, Hq = 2048;
static constexpr int BLq = Bq * Lq;  // 1024

DEV short f2bf(float f) {
  // round-to-nearest-even f32 -> bf16 (bit trick)
  unsigned u = __float_as_uint(f);
  u += 0x7fffu + ((u >> 16) & 1u);
  return (short)(u >> 16);
}

DEV float cos_fast(float t) {
  // v_cos_f32 takes REVOLUTIONS (D = cos(S0*2pi)); reduce to [0,1) first.
  float r = t * 0.15915494309189535f;  // 1/(2*pi)
#if __has_builtin(__builtin_amdgcn_fractf)
  r = __builtin_amdgcn_fractf(r);
#else
  r = r - floorf(r);
#endif
#if __has_builtin(__builtin_amdgcn_cosf)
  return __builtin_amdgcn_cosf(r);
#else
  return __cosf(r * 6.283185307179586f);
#endif
}

// ---------------------------------------------------------------------------
// K0a/K0b: transpose + convert f32 [R][C] -> bf16 [C][R]
__global__ __launch_bounds__(256) void transpose_cvt(
    const float* __restrict__ in, short* __restrict__ out, int R, int C) {
  __shared__ __align__(16) float tile[32][33];
  const int tx = threadIdx.x, ty = threadIdx.y;  // (32, 8)
  const int c0 = blockIdx.x * 32, r0 = blockIdx.y * 32;
#pragma unroll
  for (int i = 0; i < 4; ++i)
    tile[ty + 8 * i][tx] = in[(r0 + ty + 8 * i) * C + c0 + tx];
  __syncthreads();
#pragma unroll
  for (int i = 0; i < 4; ++i)
    out[(c0 + ty + 8 * i) * R + r0 + tx] = f2bf(tile[tx][ty + 8 * i]);
}

// K0c: elementwise convert f32 -> bf16 (row-major preserved)
__global__ __launch_bounds__(256) void cvt_bf16(
    const float* __restrict__ in, short* __restrict__ out) {
  const int i = (blockIdx.x * 256 + threadIdx.x) * 4;
  f32x4 v = *(const f32x4*)&in[i];
  short4v s;
  s.x = f2bf(v.x); s.y = f2bf(v.y); s.z = f2bf(v.z); s.w = f2bf(v.w);
  *(short4v*)&out[i] = s;
}

// ---------------------------------------------------------------------------
// K1: gate[bl][h] = (1/8) * sum_p cos( (x_imag[bl][p]*pos_freq[l][p]) * w[p][h] + b[p][h] )
// block: 16 bl-rows x 256 h columns. tc staged in LDS (broadcast reads).
__global__ __launch_bounds__(256) void gate_kernel(
    const float* __restrict__ x_imag, const float* __restrict__ pos_freq,
    const float* __restrict__ wq, const float* __restrict__ bq,
    float* __restrict__ gate) {
  constexpr int BLT = 16;
  __shared__ __align__(16) float tc[BLT][64];
  const int tid = threadIdx.x;
  const int bl0 = blockIdx.x * BLT;
  const int h = blockIdx.y * 256 + tid;

#pragma unroll
  for (int e = 0; e < BLT * 64 / 256; ++e) {  // 4 elems/thread
    int f = tid + 256 * e;
    int r = f >> 6, p = f & 63;
    int bl = bl0 + r;
    int l = bl & (Lq - 1);  // bl = b*L + l
    tc[r][p] = x_imag[bl * Pq + p] * pos_freq[l * Pq + p];
  }
  __syncthreads();

  float acc[BLT] = {};
#pragma unroll 1
  for (int p = 0; p < Pq; p += 4) {
    float wv0 = wq[(p + 0) * Hq + h], wv1 = wq[(p + 1) * Hq + h];
    float wv2 = wq[(p + 2) * Hq + h], wv3 = wq[(p + 3) * Hq + h];
    float bv0 = bq[(p + 0) * Hq + h], bv1 = bq[(p + 1) * Hq + h];
    float bv2 = bq[(p + 2) * Hq + h], bv3 = bq[(p + 3) * Hq + h];
#pragma unroll
    for (int r = 0; r < BLT; ++r) {
      f32x4 t = *(const f32x4*)&tc[r][p];
      acc[r] += cos_fast(t.x * wv0 + bv0);
      acc[r] += cos_fast(t.y * wv1 + bv1);
      acc[r] += cos_fast(t.z * wv2 + bv2);
      acc[r] += cos_fast(t.w * wv3 + bv3);
    }
  }
#pragma unroll
  for (int r = 0; r < BLT; ++r)
    gate[(bl0 + r) * Hq + h] = acc[r] * 0.125f;  // 1/sqrt(P)
}

// ---------------------------------------------------------------------------
// MFMA bf16 GEMM: C[M][N] = A[M][K] * Bt[N][K]^T   (Bt stored n-major, k-contiguous)
// EPI==1: obf[row*N+col] = bf16(acc * gate[row*N+col])   (value path -> out)
// EPI==2: ofl[row*N+col] = resid[row*N+col] + acc        (down proj + residual)
template <int BM, int BN, int EPI>
__global__ __launch_bounds__(256) void gemm_bf16(
    const short* __restrict__ A, const short* __restrict__ Bt, int N, int K,
    const float* __restrict__ gate, short* __restrict__ obf,
    const float* __restrict__ resid, float* __restrict__ ofl) {
  constexpr int WM = BM / 2, WN = BN / 2;   // 2x2 wave grid
  constexpr int FM = WM / 16, FN = WN / 16;
  __shared__ __align__(16) short As[BM * 32];
  __shared__ __align__(16) short Bs[BN * 32];

  const int tid = threadIdx.x;
  const int lane = tid & 63;
  const int wv = tid >> 6;
  const int wr = wv >> 1, wc = wv & 1;
  const int m0 = blockIdx.x * BM, n0 = blockIdx.y * BN;
  const int lrow = lane & 15;
  const int lk = (lane >> 4) * 8;  // A/B frag: 8 contiguous k per lane

  f32x4 acc[FM][FN] = {};

  for (int k0 = 0; k0 < K; k0 += 32) {
    if (tid < BM * 4) {
      int row = tid >> 2, seg = tid & 3;
      *(short8v*)&As[row * 32 + seg * 8] =
          *(const short8v*)&A[(m0 + row) * K + k0 + seg * 8];
    }
    if (tid < BN * 4) {
      int row = tid >> 2, seg = tid & 3;
      *(short8v*)&Bs[row * 32 + seg * 8] =
          *(const short8v*)&Bt[(n0 + row) * K + k0 + seg * 8];
    }
    __syncthreads();
    short8v a[FM], bfrag[FN];
#pragma unroll
    for (int i = 0; i < FM; ++i)
      a[i] = *(const short8v*)&As[(wr * WM + i * 16 + lrow) * 32 + lk];
#pragma unroll
    for (int j = 0; j < FN; ++j)
      bfrag[j] = *(const short8v*)&Bs[(wc * WN + j * 16 + lrow) * 32 + lk];
#pragma unroll
    for (int i = 0; i < FM; ++i)
#pragma unroll
      for (int j = 0; j < FN; ++j)
        acc[i][j] = __builtin_amdgcn_mfma_f32_16x16x32_bf16(
            a[i], bfrag[j], acc[i][j], 0, 0, 0);
    __syncthreads();
  }

  // C/D layout (m89-verified): col = lane&15, row = (lane>>4)*4 + reg
#pragma unroll
  for (int i = 0; i < FM; ++i)
#pragma unroll
    for (int j = 0; j < FN; ++j)
#pragma unroll
      for (int r = 0; r < 4; ++r) {
        int row = m0 + wr * WM + i * 16 + (lane >> 4) * 4 + r;
        int col = n0 + wc * WN + j * 16 + lrow;
        float v = acc[i][j][r];
        if constexpr (EPI == 1) {
          obf[row * N + col] = f2bf(v * gate[row * N + col]);
        } else {
          ofl[row * N + col] = resid[row * N + col] + v;
        }
      }
}

// ---------------------------------------------------------------------------
// K4: out_imag[bl][p] = x_imag[bl][p] + sum_h gate[bl][h] * Wdi[h][p]
__global__ __launch_bounds__(256) void imag_kernel(
    const float* __restrict__ gate, const float* __restrict__ Wdi,
    const float* __restrict__ x_imag, float* __restrict__ out_imag) {
  const int tid = threadIdx.x;
  const int r = tid >> 6, p = tid & 63;
  const int bl = blockIdx.x * 4 + r;
  const float* g = &gate[bl * Hq];
  float acc = 0.f;
#pragma unroll 4
  for (int hh = 0; hh < Hq; hh += 4) {
    f32x4 g4 = *(const f32x4*)&g[hh];
    acc += g4.x * Wdi[(hh + 0) * Pq + p];
    acc += g4.y * Wdi[(hh + 1) * Pq + p];
    acc += g4.z * Wdi[(hh + 2) * Pq + p];
    acc += g4.w * Wdi[(hh + 3) * Pq + p];
  }
  out_imag[bl * Pq + p] = x_imag[bl * Pq + p] + acc;
}

// ---------------------------------------------------------------------------
extern "C" void kernel_launch(void* const* d_in, const int* in_sizes, int n_in,
                              void* d_out, int out_size, void* d_ws,
                              size_t ws_size, hipStream_t stream) {
  const float* x_real   = (const float*)d_in[0];  // (B,L,D) 524288
  const float* x_imag   = (const float*)d_in[1];  // (B,L,P) 65536
  const float* pos_freq = (const float*)d_in[2];  // (L,P)   32768
  const float* W_up     = (const float*)d_in[3];  // (D,H)
  const float* wq       = (const float*)d_in[4];  // (P,H)
  const float* bq       = (const float*)d_in[5];  // (P,H)
  const float* Wdr      = (const float*)d_in[6];  // (H,D)
  const float* Wdi      = (const float*)d_in[7];  // (H,P)

  float* out_real = (float*)d_out;            // (B,L,D)
  float* out_imag = out_real + BLq * Dq;      // (B,L,P)

  char* ws = (char*)d_ws;
  float* gate  = (float*)ws;                        // 8 MB  [BL][H] f32
  short* outbf = (short*)(ws + (8u << 20));         // 4 MB  [BL][H] bf16
  short* wupT  = (short*)(ws + (12u << 20));        // 2 MB  [H][D]  bf16
  short* wdrT  = (short*)(ws + (14u << 20));        // 2 MB  [D][H]  bf16
  short* xrbf  = (short*)(ws + (16u << 20));        // 1 MB  [BL][D] bf16

  // weight transposes + input convert (k-contiguous operands for MFMA)
  transpose_cvt<<<dim3(Hq / 32, Dq / 32), dim3(32, 8), 0, stream>>>(W_up, wupT, Dq, Hq);
  transpose_cvt<<<dim3(Dq / 32, Hq / 32), dim3(32, 8), 0, stream>>>(Wdr, wdrT, Hq, Dq);
  cvt_bf16<<<(BLq * Dq) / 1024, 256, 0, stream>>>(x_real, xrbf);

  // gate
  gate_kernel<<<dim3(BLq / 16, Hq / 256), 256, 0, stream>>>(x_imag, pos_freq, wq, bq, gate);

  // out = (x_real @ W_up) * gate   -> bf16
  gemm_bf16<64, 64, 1><<<dim3(BLq / 64, Hq / 64), 256, 0, stream>>>(
      xrbf, wupT, Hq, Dq, gate, outbf, nullptr, nullptr);

  // out_real = x_real + out @ W_down_real
  gemm_bf16<64, 32, 2><<<dim3(BLq / 64, Dq / 32), 256, 0, stream>>>(
      outbf, wdrT, Dq, Hq, nullptr, nullptr, x_real, out_real);

  // out_imag = x_imag + gate @ W_down_imag
  imag_kernel<<<BLq / 4, 256, 0, stream>>>(gate, Wdi, x_imag, out_imag);
}

// Round 5
// 190.537 us; speedup vs baseline: 1.0320x; 1.0320x over previous
//
#include <hip/hip_runtime.h>

#define DEV __device__ __forceinline__

typedef __attribute__((ext_vector_type(4))) float  f32x4;
typedef __attribute__((ext_vector_type(8))) short  short8v;
typedef __attribute__((ext_vector_type(4))) short  short4v;

// Problem sizes (fixed by the reference)
static constexpr int Bq = 2, Lq = 512, Dq = 512, Pq = 64, Hq = 2048;
static constexpr int BLq = Bq * Lq;  // 1024
static constexpr float INV2PI = 0.15915494309189535f;

DEV short f2bf(float f) {
  // round-to-nearest-even f32 -> bf16 (bit trick)
  unsigned u = __float_as_uint(f);
  u += 0x7fffu + ((u >> 16) & 1u);
  return (short)(u >> 16);
}

// cos of t given in REVOLUTIONS (arg pre-scaled by 1/2pi)
DEV float cos_rev(float t) {
#if __has_builtin(__builtin_amdgcn_fractf) && __has_builtin(__builtin_amdgcn_cosf)
  return __builtin_amdgcn_cosf(__builtin_amdgcn_fractf(t));
#else
  return __cosf((t - floorf(t)) * 6.283185307179586f);
#endif
}

// async global->LDS, 16 bytes per lane. LDS dest must be linear in lane
// (wave-uniform base + lane*16) -- caller guarantees.
DEV void gload_lds16(const void* g, void* l) {
  __builtin_amdgcn_global_load_lds(
      (const __attribute__((address_space(1))) void*)g,
      (__attribute__((address_space(3))) void*)l, 16, 0, 0);
}

// ---------------------------------------------------------------------------
// K0a/K0b: transpose + convert f32 [R][C] -> bf16 [C][R]
__global__ __launch_bounds__(256) void transpose_cvt(
    const float* __restrict__ in, short* __restrict__ out, int R, int C) {
  __shared__ __align__(16) float tile[32][33];
  const int tx = threadIdx.x, ty = threadIdx.y;  // (32, 8)
  const int c0 = blockIdx.x * 32, r0 = blockIdx.y * 32;
#pragma unroll
  for (int i = 0; i < 4; ++i)
    tile[ty + 8 * i][tx] = in[(r0 + ty + 8 * i) * C + c0 + tx];
  __syncthreads();
#pragma unroll
  for (int i = 0; i < 4; ++i)
    out[(c0 + ty + 8 * i) * R + r0 + tx] = f2bf(tile[tx][ty + 8 * i]);
}

// K0c: elementwise convert f32 -> bf16 (row-major preserved)
__global__ __launch_bounds__(256) void cvt_bf16(
    const float* __restrict__ in, short* __restrict__ out) {
  const int i = (blockIdx.x * 256 + threadIdx.x) * 4;
  f32x4 v = *(const f32x4*)&in[i];
  short4v s;
  s.x = f2bf(v.x); s.y = f2bf(v.y); s.z = f2bf(v.z); s.w = f2bf(v.w);
  *(short4v*)&out[i] = s;
}

// ---------------------------------------------------------------------------
// K1: gate[bl][h] = (1/8) * sum_p cos( (x_imag[bl][p]*pos_freq[l][p]) * w[p][h] + b[p][h] )
// block: 16 bl-rows x 256 h columns. tc staged in LDS (broadcast reads).
// w/b pre-scaled by 1/(2pi) at register load so per-element work is
// fma + fract + cos + add (no per-element radian->rev multiply).
__global__ __launch_bounds__(256) void gate_kernel(
    const float* __restrict__ x_imag, const float* __restrict__ pos_freq,
    const float* __restrict__ wq, const float* __restrict__ bq,
    float* __restrict__ gate) {
  constexpr int BLT = 16;
  __shared__ __align__(16) float tc[BLT][64];
  const int tid = threadIdx.x;
  const int bl0 = blockIdx.x * BLT;
  const int h = blockIdx.y * 256 + tid;

#pragma unroll
  for (int e = 0; e < BLT * 64 / 256; ++e) {  // 4 elems/thread
    int f = tid + 256 * e;
    int r = f >> 6, p = f & 63;
    int bl = bl0 + r;
    int l = bl & (Lq - 1);  // bl = b*L + l
    tc[r][p] = x_imag[bl * Pq + p] * pos_freq[l * Pq + p];
  }
  __syncthreads();

  float acc[BLT] = {};
#pragma unroll 1
  for (int p = 0; p < Pq; p += 4) {
    float wv0 = wq[(p + 0) * Hq + h] * INV2PI, wv1 = wq[(p + 1) * Hq + h] * INV2PI;
    float wv2 = wq[(p + 2) * Hq + h] * INV2PI, wv3 = wq[(p + 3) * Hq + h] * INV2PI;
    float bv0 = bq[(p + 0) * Hq + h] * INV2PI, bv1 = bq[(p + 1) * Hq + h] * INV2PI;
    float bv2 = bq[(p + 2) * Hq + h] * INV2PI, bv3 = bq[(p + 3) * Hq + h] * INV2PI;
#pragma unroll
    for (int r = 0; r < BLT; ++r) {
      f32x4 t = *(const f32x4*)&tc[r][p];
      acc[r] += cos_rev(t.x * wv0 + bv0);
      acc[r] += cos_rev(t.y * wv1 + bv1);
      acc[r] += cos_rev(t.z * wv2 + bv2);
      acc[r] += cos_rev(t.w * wv3 + bv3);
    }
  }
#pragma unroll
  for (int r = 0; r < BLT; ++r)
    gate[(bl0 + r) * Hq + h] = acc[r] * 0.125f;  // 1/sqrt(P)
}

// ---------------------------------------------------------------------------
// MFMA bf16 GEMM: C[M][N] = A[M][K] * Bt[N][K]^T   (Bt stored n-major, k-contiguous)
// Staging via global_load_lds width=16: LDS byte offset for thread tid is
// exactly 16*tid (linear in lane), matching the HW wave-uniform-base+lane*16
// destination rule (m104/m108). __syncthreads drains vmcnt before use.
// EPI==1: obf[row*N+col] = bf16(acc * gate[row*N+col])   (value path -> out)
// EPI==2: ofl[row*N+col] = resid[row*N+col] + acc        (down proj + residual)
template <int BM, int BN, int EPI>
__global__ __launch_bounds__(256) void gemm_bf16(
    const short* __restrict__ A, const short* __restrict__ Bt, int N, int K,
    const float* __restrict__ gate, short* __restrict__ obf,
    const float* __restrict__ resid, float* __restrict__ ofl) {
  constexpr int WM = BM / 2, WN = BN / 2;   // 2x2 wave grid
  constexpr int FM = WM / 16, FN = WN / 16;
  __shared__ __align__(16) short As[BM * 32];
  __shared__ __align__(16) short Bs[BN * 32];

  const int tid = threadIdx.x;
  const int lane = tid & 63;
  const int wv = tid >> 6;
  const int wr = wv >> 1, wc = wv & 1;
  const int m0 = blockIdx.x * BM, n0 = blockIdx.y * BN;
  const int lrow = lane & 15;
  const int lk = (lane >> 4) * 8;  // A/B frag: 8 contiguous k per lane
  const int srow = tid >> 2, sseg = tid & 3;  // staging: row, 8-short segment

  f32x4 acc[FM][FN] = {};

  for (int k0 = 0; k0 < K; k0 += 32) {
    // async stage: 16B/lane, LDS offset = 16*tid (linear)
    gload_lds16(&A[(m0 + srow) * K + k0 + sseg * 8], &As[tid * 8]);
    if (tid < BN * 4)
      gload_lds16(&Bt[(n0 + srow) * K + k0 + sseg * 8], &Bs[tid * 8]);
    __syncthreads();

    short8v a[FM], bfrag[FN];
#pragma unroll
    for (int i = 0; i < FM; ++i)
      a[i] = *(const short8v*)&As[(wr * WM + i * 16 + lrow) * 32 + lk];
#pragma unroll
    for (int j = 0; j < FN; ++j)
      bfrag[j] = *(const short8v*)&Bs[(wc * WN + j * 16 + lrow) * 32 + lk];
#pragma unroll
    for (int i = 0; i < FM; ++i)
#pragma unroll
      for (int j = 0; j < FN; ++j)
        acc[i][j] = __builtin_amdgcn_mfma_f32_16x16x32_bf16(
            a[i], bfrag[j], acc[i][j], 0, 0, 0);
    __syncthreads();
  }

  // C/D layout (m89-verified): col = lane&15, row = (lane>>4)*4 + reg
#pragma unroll
  for (int i = 0; i < FM; ++i)
#pragma unroll
    for (int j = 0; j < FN; ++j)
#pragma unroll
      for (int r = 0; r < 4; ++r) {
        int row = m0 + wr * WM + i * 16 + (lane >> 4) * 4 + r;
        int col = n0 + wc * WN + j * 16 + lrow;
        float v = acc[i][j][r];
        if constexpr (EPI == 1) {
          obf[row * N + col] = f2bf(v * gate[row * N + col]);
        } else {
          ofl[row * N + col] = resid[row * N + col] + v;
        }
      }
}

// ---------------------------------------------------------------------------
// K4: out_imag[bl][p] = x_imag[bl][p] + sum_h gate[bl][h] * Wdi[h][p]
// 8 rows/block, 512 threads = (kchunk 0..7) x (p 0..63).
// Each thread: 8 independent row-accumulators over a 256-wide K-chunk
// (8-way ILP; Wdi load reused across 8 rows; gate loads wave-uniform).
// Cross-chunk reduction via 16 KB LDS.
__global__ __launch_bounds__(512) void imag_kernel(
    const float* __restrict__ gate, const float* __restrict__ Wdi,
    const float* __restrict__ x_imag, float* __restrict__ out_imag) {
  constexpr int ROWS = 8, KC = 8, KLEN = Hq / KC;  // 256
  __shared__ float red[KC][ROWS][Pq];
  const int tid = threadIdx.x;
  const int p = tid & 63;
  const int kc = tid >> 6;           // wave index = K-chunk
  const int bl0 = blockIdx.x * ROWS;

  float acc[ROWS] = {};
  const int h0 = kc * KLEN;
#pragma unroll 2
  for (int hh = h0; hh < h0 + KLEN; hh += 4) {
    float w0 = Wdi[(hh + 0) * Pq + p];
    float w1 = Wdi[(hh + 1) * Pq + p];
    float w2 = Wdi[(hh + 2) * Pq + p];
    float w3 = Wdi[(hh + 3) * Pq + p];
#pragma unroll
    for (int r = 0; r < ROWS; ++r) {
      f32x4 g4 = *(const f32x4*)&gate[(bl0 + r) * Hq + hh];  // wave-uniform
      acc[r] += g4.x * w0 + g4.y * w1 + g4.z * w2 + g4.w * w3;
    }
  }
#pragma unroll
  for (int r = 0; r < ROWS; ++r) red[kc][r][p] = acc[r];
  __syncthreads();

  // 512 threads -> 512 outputs (r = tid>>6, p = tid&63), each sums 8 partials
  const int r = tid >> 6;
  float s = 0.f;
#pragma unroll
  for (int k = 0; k < KC; ++k) s += red[k][r][p];
  const int idx = (bl0 + r) * Pq + p;
  out_imag[idx] = x_imag[idx] + s;
}

// ---------------------------------------------------------------------------
extern "C" void kernel_launch(void* const* d_in, const int* in_sizes, int n_in,
                              void* d_out, int out_size, void* d_ws,
                              size_t ws_size, hipStream_t stream) {
  const float* x_real   = (const float*)d_in[0];  // (B,L,D) 524288
  const float* x_imag   = (const float*)d_in[1];  // (B,L,P) 65536
  const float* pos_freq = (const float*)d_in[2];  // (L,P)   32768
  const float* W_up     = (const float*)d_in[3];  // (D,H)
  const float* wq       = (const float*)d_in[4];  // (P,H)
  const float* bq       = (const float*)d_in[5];  // (P,H)
  const float* Wdr      = (const float*)d_in[6];  // (H,D)
  const float* Wdi      = (const float*)d_in[7];  // (H,P)

  float* out_real = (float*)d_out;            // (B,L,D)
  float* out_imag = out_real + BLq * Dq;      // (B,L,P)

  char* ws = (char*)d_ws;
  float* gate  = (float*)ws;                        // 8 MB  [BL][H] f32
  short* outbf = (short*)(ws + (8u << 20));         // 4 MB  [BL][H] bf16
  short* wupT  = (short*)(ws + (12u << 20));        // 2 MB  [H][D]  bf16
  short* wdrT  = (short*)(ws + (14u << 20));        // 2 MB  [D][H]  bf16
  short* xrbf  = (short*)(ws + (16u << 20));        // 1 MB  [BL][D] bf16

  // weight transposes + input convert (k-contiguous operands for MFMA)
  transpose_cvt<<<dim3(Hq / 32, Dq / 32), dim3(32, 8), 0, stream>>>(W_up, wupT, Dq, Hq);
  transpose_cvt<<<dim3(Dq / 32, Hq / 32), dim3(32, 8), 0, stream>>>(Wdr, wdrT, Hq, Dq);
  cvt_bf16<<<(BLq * Dq) / 1024, 256, 0, stream>>>(x_real, xrbf);

  // gate
  gate_kernel<<<dim3(BLq / 16, Hq / 256), 256, 0, stream>>>(x_imag, pos_freq, wq, bq, gate);

  // out = (x_real @ W_up) * gate   -> bf16
  gemm_bf16<64, 64, 1><<<dim3(BLq / 64, Hq / 64), 256, 0, stream>>>(
      xrbf, wupT, Hq, Dq, gate, outbf, nullptr, nullptr);

  // out_real = x_real + out @ W_down_real
  gemm_bf16<64, 32, 2><<<dim3(BLq / 64, Dq / 32), 256, 0, stream>>>(
      outbf, wdrT, Dq, Hq, nullptr, nullptr, x_real, out_real);

  // out_imag = x_imag + gate @ W_down_imag
  imag_kernel<<<BLq / 8, 512, 0, stream>>>(gate, Wdi, x_imag, out_imag);
}

// Round 6
// 147.851 us; speedup vs baseline: 1.3299x; 1.2887x over previous
//
#include <hip/hip_runtime.h>

#define DEV __device__ __forceinline__

typedef __attribute__((ext_vector_type(4))) float  f32x4;
typedef __attribute__((ext_vector_type(8))) short  short8v;
typedef __attribute__((ext_vector_type(4))) short  short4v;

// Problem sizes (fixed by the reference)
static constexpr int Bq = 2, Lq = 512, Dq = 512, Pq = 64, Hq = 2048;
static constexpr int BLq = Bq * Lq;  // 1024
static constexpr float INV2PI = 0.15915494309189535f;

DEV short f2bf(float f) {
  // round-to-nearest-even f32 -> bf16 (bit trick)
  unsigned u = __float_as_uint(f);
  u += 0x7fffu + ((u >> 16) & 1u);
  return (short)(u >> 16);
}
DEV float bf2f(short s) {
  return __uint_as_float(((unsigned)(unsigned short)s) << 16);
}

// cos of t given in REVOLUTIONS (arg pre-scaled by 1/2pi)
DEV float cos_rev(float t) {
#if __has_builtin(__builtin_amdgcn_fractf) && __has_builtin(__builtin_amdgcn_cosf)
  return __builtin_amdgcn_cosf(__builtin_amdgcn_fractf(t));
#else
  return __cosf((t - floorf(t)) * 6.283185307179586f);
#endif
}

// async global->LDS, 16 bytes per lane. LDS dest must be linear in lane
// (wave-uniform base + lane*16) -- caller guarantees.
DEV void gload_lds16(const void* g, void* l) {
  __builtin_amdgcn_global_load_lds(
      (const __attribute__((address_space(1))) void*)g,
      (__attribute__((address_space(3))) void*)l, 16, 0, 0);
}

// ---------------------------------------------------------------------------
// K0a/K0b/K0d: transpose + convert f32 [R][C] -> bf16 [C][R]
__global__ __launch_bounds__(256) void transpose_cvt(
    const float* __restrict__ in, short* __restrict__ out, int R, int C) {
  __shared__ __align__(16) float tile[32][33];
  const int tx = threadIdx.x, ty = threadIdx.y;  // (32, 8)
  const int c0 = blockIdx.x * 32, r0 = blockIdx.y * 32;
#pragma unroll
  for (int i = 0; i < 4; ++i)
    tile[ty + 8 * i][tx] = in[(r0 + ty + 8 * i) * C + c0 + tx];
  __syncthreads();
#pragma unroll
  for (int i = 0; i < 4; ++i)
    out[(c0 + ty + 8 * i) * R + r0 + tx] = f2bf(tile[tx][ty + 8 * i]);
}

// K0c: elementwise convert f32 -> bf16 (row-major preserved)
__global__ __launch_bounds__(256) void cvt_bf16(
    const float* __restrict__ in, short* __restrict__ out) {
  const int i = (blockIdx.x * 256 + threadIdx.x) * 4;
  f32x4 v = *(const f32x4*)&in[i];
  short4v s;
  s.x = f2bf(v.x); s.y = f2bf(v.y); s.z = f2bf(v.z); s.w = f2bf(v.w);
  *(short4v*)&out[i] = s;
}

// ---------------------------------------------------------------------------
// K1: gate[bl][h] = (1/8) * sum_p cos( (x_imag[bl][p]*pos_freq[l][p]) * w[p][h] + b[p][h] )
// block: 16 bl-rows x 256 h columns. tc staged in LDS (broadcast reads).
// Output is bf16 (consumers: gemm1 epilogue + imag MFMA GEMM).
__global__ __launch_bounds__(256) void gate_kernel(
    const float* __restrict__ x_imag, const float* __restrict__ pos_freq,
    const float* __restrict__ wq, const float* __restrict__ bq,
    short* __restrict__ gate) {
  constexpr int BLT = 16;
  __shared__ __align__(16) float tc[BLT][64];
  const int tid = threadIdx.x;
  const int bl0 = blockIdx.x * BLT;
  const int h = blockIdx.y * 256 + tid;

#pragma unroll
  for (int e = 0; e < BLT * 64 / 256; ++e) {  // 4 elems/thread
    int f = tid + 256 * e;
    int r = f >> 6, p = f & 63;
    int bl = bl0 + r;
    int l = bl & (Lq - 1);  // bl = b*L + l
    tc[r][p] = x_imag[bl * Pq + p] * pos_freq[l * Pq + p];
  }
  __syncthreads();

  float acc[BLT] = {};
#pragma unroll 1
  for (int p = 0; p < Pq; p += 4) {
    float wv0 = wq[(p + 0) * Hq + h] * INV2PI, wv1 = wq[(p + 1) * Hq + h] * INV2PI;
    float wv2 = wq[(p + 2) * Hq + h] * INV2PI, wv3 = wq[(p + 3) * Hq + h] * INV2PI;
    float bv0 = bq[(p + 0) * Hq + h] * INV2PI, bv1 = bq[(p + 1) * Hq + h] * INV2PI;
    float bv2 = bq[(p + 2) * Hq + h] * INV2PI, bv3 = bq[(p + 3) * Hq + h] * INV2PI;
#pragma unroll
    for (int r = 0; r < BLT; ++r) {
      f32x4 t = *(const f32x4*)&tc[r][p];
      acc[r] += cos_rev(t.x * wv0 + bv0);
      acc[r] += cos_rev(t.y * wv1 + bv1);
      acc[r] += cos_rev(t.z * wv2 + bv2);
      acc[r] += cos_rev(t.w * wv3 + bv3);
    }
  }
#pragma unroll
  for (int r = 0; r < BLT; ++r)
    gate[(bl0 + r) * Hq + h] = f2bf(acc[r] * 0.125f);  // 1/sqrt(P)
}

// ---------------------------------------------------------------------------
// MFMA bf16 GEMM: C[M][N] = A[M][K] * Bt[N][K]^T   (Bt stored n-major, k-contiguous)
// Staging via global_load_lds width=16: LDS byte offset = 16*tid (linear in
// lane), matching the wave-uniform-base+lane*16 destination rule (m104/m108).
// EPI==1: obf[row*N+col] = bf16(acc * gate_bf16[row*N+col])  (value path)
// EPI==2: ofl[row*N+col] = resid[row*N+col] + acc            (down proj + resid)
template <int BM, int BN, int EPI>
__global__ __launch_bounds__(256) void gemm_bf16(
    const short* __restrict__ A, const short* __restrict__ Bt, int N, int K,
    const short* __restrict__ gate, short* __restrict__ obf,
    const float* __restrict__ resid, float* __restrict__ ofl) {
  constexpr int WM = BM / 2, WN = BN / 2;   // 2x2 wave grid
  constexpr int FM = WM / 16, FN = WN / 16;
  __shared__ __align__(16) short As[BM * 32];
  __shared__ __align__(16) short Bs[BN * 32];

  const int tid = threadIdx.x;
  const int lane = tid & 63;
  const int wv = tid >> 6;
  const int wr = wv >> 1, wc = wv & 1;
  const int m0 = blockIdx.x * BM, n0 = blockIdx.y * BN;
  const int lrow = lane & 15;
  const int lk = (lane >> 4) * 8;  // A/B frag: 8 contiguous k per lane
  const int srow = tid >> 2, sseg = tid & 3;  // staging: row, 8-short segment

  f32x4 acc[FM][FN] = {};

  for (int k0 = 0; k0 < K; k0 += 32) {
    gload_lds16(&A[(m0 + srow) * K + k0 + sseg * 8], &As[tid * 8]);
    if (tid < BN * 4)
      gload_lds16(&Bt[(n0 + srow) * K + k0 + sseg * 8], &Bs[tid * 8]);
    __syncthreads();

    short8v a[FM], bfrag[FN];
#pragma unroll
    for (int i = 0; i < FM; ++i)
      a[i] = *(const short8v*)&As[(wr * WM + i * 16 + lrow) * 32 + lk];
#pragma unroll
    for (int j = 0; j < FN; ++j)
      bfrag[j] = *(const short8v*)&Bs[(wc * WN + j * 16 + lrow) * 32 + lk];
#pragma unroll
    for (int i = 0; i < FM; ++i)
#pragma unroll
      for (int j = 0; j < FN; ++j)
        acc[i][j] = __builtin_amdgcn_mfma_f32_16x16x32_bf16(
            a[i], bfrag[j], acc[i][j], 0, 0, 0);
    __syncthreads();
  }

  // C/D layout (m89-verified): col = lane&15, row = (lane>>4)*4 + reg
#pragma unroll
  for (int i = 0; i < FM; ++i)
#pragma unroll
    for (int j = 0; j < FN; ++j)
#pragma unroll
      for (int r = 0; r < 4; ++r) {
        int row = m0 + wr * WM + i * 16 + (lane >> 4) * 4 + r;
        int col = n0 + wc * WN + j * 16 + lrow;
        float v = acc[i][j][r];
        if constexpr (EPI == 1) {
          obf[row * N + col] = f2bf(v * bf2f(gate[row * N + col]));
        } else {
          ofl[row * N + col] = resid[row * N + col] + v;
        }
      }
}

// ---------------------------------------------------------------------------
// K4a: split-K MFMA GEMM for the imag path.
// part[ks][m0+row][col] = gate_bf[m-tile][k-chunk] @ wdiT[64][k-chunk]^T
// grid: (M/64 = 16, KS = 16) -> 256 blocks (full GPU), 4 k-steps each.
__global__ __launch_bounds__(256) void imag_gemm(
    const short* __restrict__ A,   // gate_bf [BL][H]
    const short* __restrict__ Bt,  // wdiT [64][H]
    float* __restrict__ part) {    // [KS][BL][64]
  constexpr int BM = 64, BN = 64, KS = 16, KLEN = Hq / KS;  // 128
  constexpr int WM = BM / 2, WN = BN / 2, FM = WM / 16, FN = WN / 16;
  __shared__ __align__(16) short As[BM * 32];
  __shared__ __align__(16) short Bs[BN * 32];

  const int tid = threadIdx.x;
  const int lane = tid & 63;
  const int wv = tid >> 6;
  const int wr = wv >> 1, wc = wv & 1;
  const int m0 = blockIdx.x * BM;
  const int kb = blockIdx.y * KLEN;
  const int lrow = lane & 15;
  const int lk = (lane >> 4) * 8;
  const int srow = tid >> 2, sseg = tid & 3;

  f32x4 acc[FM][FN] = {};

  for (int k0 = kb; k0 < kb + KLEN; k0 += 32) {
    gload_lds16(&A[(m0 + srow) * Hq + k0 + sseg * 8], &As[tid * 8]);
    gload_lds16(&Bt[srow * Hq + k0 + sseg * 8], &Bs[tid * 8]);
    __syncthreads();

    short8v a[FM], bfrag[FN];
#pragma unroll
    for (int i = 0; i < FM; ++i)
      a[i] = *(const short8v*)&As[(wr * WM + i * 16 + lrow) * 32 + lk];
#pragma unroll
    for (int j = 0; j < FN; ++j)
      bfrag[j] = *(const short8v*)&Bs[(wc * WN + j * 16 + lrow) * 32 + lk];
#pragma unroll
    for (int i = 0; i < FM; ++i)
#pragma unroll
      for (int j = 0; j < FN; ++j)
        acc[i][j] = __builtin_amdgcn_mfma_f32_16x16x32_bf16(
            a[i], bfrag[j], acc[i][j], 0, 0, 0);
    __syncthreads();
  }

  float* p = &part[blockIdx.y * (BLq * Pq)];
#pragma unroll
  for (int i = 0; i < FM; ++i)
#pragma unroll
    for (int j = 0; j < FN; ++j)
#pragma unroll
      for (int r = 0; r < 4; ++r) {
        int row = m0 + wr * WM + i * 16 + (lane >> 4) * 4 + r;
        int col = wc * WN + j * 16 + lrow;
        p[row * Pq + col] = acc[i][j][r];
      }
}

// K4b: out_imag = x_imag + sum_ks part[ks]
__global__ __launch_bounds__(256) void imag_reduce(
    const float* __restrict__ part, const float* __restrict__ x_imag,
    float* __restrict__ out_imag) {
  const int off = (blockIdx.x * 256 + threadIdx.x) * 4;
  f32x4 s = *(const f32x4*)&x_imag[off];
#pragma unroll
  for (int ks = 0; ks < 16; ++ks) {
    f32x4 p4 = *(const f32x4*)&part[ks * (BLq * Pq) + off];
    s.x += p4.x; s.y += p4.y; s.z += p4.z; s.w += p4.w;
  }
  *(f32x4*)&out_imag[off] = s;
}

// ---------------------------------------------------------------------------
extern "C" void kernel_launch(void* const* d_in, const int* in_sizes, int n_in,
                              void* d_out, int out_size, void* d_ws,
                              size_t ws_size, hipStream_t stream) {
  const float* x_real   = (const float*)d_in[0];  // (B,L,D)
  const float* x_imag   = (const float*)d_in[1];  // (B,L,P)
  const float* pos_freq = (const float*)d_in[2];  // (L,P)
  const float* W_up     = (const float*)d_in[3];  // (D,H)
  const float* wq       = (const float*)d_in[4];  // (P,H)
  const float* bq       = (const float*)d_in[5];  // (P,H)
  const float* Wdr      = (const float*)d_in[6];  // (H,D)
  const float* Wdi      = (const float*)d_in[7];  // (H,P)

  float* out_real = (float*)d_out;            // (B,L,D)
  float* out_imag = out_real + BLq * Dq;      // (B,L,P)

  char* ws = (char*)d_ws;
  short* gate_bf = (short*)ws;                      // 4 MB  [BL][H] bf16
  short* outbf   = (short*)(ws + (4u << 20));       // 4 MB  [BL][H] bf16
  short* wupT    = (short*)(ws + (8u << 20));       // 2 MB  [H][D]  bf16
  short* wdrT    = (short*)(ws + (10u << 20));      // 2 MB  [D][H]  bf16
  short* xrbf    = (short*)(ws + (12u << 20));      // 1 MB  [BL][D] bf16
  short* wdiT    = (short*)(ws + (13u << 20));      // 256KB [P][H]  bf16
  // part aliases wupT/wdrT (both dead after gemm2, stream-ordered before imag_gemm)
  float* part    = (float*)(ws + (8u << 20));       // 4 MB  [16][BL][P] f32

  // weight transposes + input convert (k-contiguous operands for MFMA)
  transpose_cvt<<<dim3(Hq / 32, Dq / 32), dim3(32, 8), 0, stream>>>(W_up, wupT, Dq, Hq);
  transpose_cvt<<<dim3(Dq / 32, Hq / 32), dim3(32, 8), 0, stream>>>(Wdr, wdrT, Hq, Dq);
  transpose_cvt<<<dim3(Pq / 32, Hq / 32), dim3(32, 8), 0, stream>>>(Wdi, wdiT, Hq, Pq);
  cvt_bf16<<<(BLq * Dq) / 1024, 256, 0, stream>>>(x_real, xrbf);

  // gate (bf16 out)
  gate_kernel<<<dim3(BLq / 16, Hq / 256), 256, 0, stream>>>(x_imag, pos_freq, wq, bq, gate_bf);

  // out = (x_real @ W_up) * gate   -> bf16
  gemm_bf16<64, 64, 1><<<dim3(BLq / 64, Hq / 64), 256, 0, stream>>>(
      xrbf, wupT, Hq, Dq, gate_bf, outbf, nullptr, nullptr);

  // out_real = x_real + out @ W_down_real
  gemm_bf16<64, 32, 2><<<dim3(BLq / 64, Dq / 32), 256, 0, stream>>>(
      outbf, wdrT, Dq, Hq, nullptr, nullptr, x_real, out_real);

  // out_imag = x_imag + gate @ W_down_imag   (split-K MFMA + reduce)
  imag_gemm<<<dim3(BLq / 64, 16), 256, 0, stream>>>(gate_bf, wdiT, part);
  imag_reduce<<<(BLq * Pq) / 1024, 256, 0, stream>>>(part, x_imag, out_imag);
}

// Round 11
// 129.153 us; speedup vs baseline: 1.5225x; 1.1448x over previous
//
#include <hip/hip_runtime.h>

#define DEV __device__ __forceinline__

typedef __attribute__((ext_vector_type(4))) float  f32x4;
typedef __attribute__((ext_vector_type(8))) short  short8v;
typedef __attribute__((ext_vector_type(4))) short  short4v;

// Problem sizes (fixed by the reference)
static constexpr int Bq = 2, Lq = 512, Dq = 512, Pq = 64, Hq = 2048;
static constexpr int BLq = Bq * Lq;  // 1024
static constexpr float INV2PI = 0.15915494309189535f;

DEV short f2bf(float f) {
  unsigned u = __float_as_uint(f);
  u += 0x7fffu + ((u >> 16) & 1u);
  return (short)(u >> 16);
}
DEV float bf2f(short s) {
  return __uint_as_float(((unsigned)(unsigned short)s) << 16);
}

// cos of t given in REVOLUTIONS (arg pre-scaled by 1/2pi)
DEV float cos_rev(float t) {
#if __has_builtin(__builtin_amdgcn_fractf) && __has_builtin(__builtin_amdgcn_cosf)
  return __builtin_amdgcn_cosf(__builtin_amdgcn_fractf(t));
#else
  return __cosf((t - floorf(t)) * 6.283185307179586f);
#endif
}

// async global->LDS, 16B/lane; LDS dest linear in lane (wave base + lane*16)
DEV void gload_lds16(const void* g, void* l) {
  __builtin_amdgcn_global_load_lds(
      (const __attribute__((address_space(1))) void*)g,
      (__attribute__((address_space(3))) void*)l, 16, 0, 0);
}

// ---------------------------------------------------------------------------
// Kernel A: fused prologue. Role-split by blockIdx.x (roles independent):
//   [0,1024)    transpose W_up  f32[512][2048]  -> wupT bf16[2048][512]
//   [1024,2048) transpose Wdr   f32[2048][512]  -> wdrT bf16[512][2048]
//   [2048,2176) transpose Wdi   f32[2048][64]   -> wdiT bf16[64][2048]
//   [2176,2688) cvt x_real -> xrbf bf16
//   [2688,3200) gate: gate_bf[bl][h] = bf16( (1/8) sum_p cos(tc*w + b) )
__global__ __launch_bounds__(256) void fused_prologue(
    const float* __restrict__ x_real, const float* __restrict__ x_imag,
    const float* __restrict__ pos_freq,
    const float* __restrict__ W_up, const float* __restrict__ wq,
    const float* __restrict__ bq, const float* __restrict__ Wdr,
    const float* __restrict__ Wdi,
    short* __restrict__ wupT, short* __restrict__ wdrT,
    short* __restrict__ wdiT, short* __restrict__ xrbf,
    short* __restrict__ gate) {
  __shared__ __align__(16) float smem[32 * 33];
  const int b = blockIdx.x, tid = threadIdx.x;

  if (b < 2176) {  // --- transpose roles ---
    const float* in; short* out; int R, C, c0, r0;
    if (b < 1024)      { in = W_up; out = wupT; R = 512;  C = 2048; c0 = (b & 63) * 32; r0 = (b >> 6) * 32; }
    else if (b < 2048) { int bb = b - 1024; in = Wdr; out = wdrT; R = 2048; C = 512; c0 = (bb & 15) * 32; r0 = (bb >> 4) * 32; }
    else               { int bb = b - 2048; in = Wdi; out = wdiT; R = 2048; C = 64;  c0 = (bb & 1) * 32;  r0 = (bb >> 1) * 32; }
    float (*tile)[33] = (float(*)[33])smem;
    const int tx = tid & 31, ty = tid >> 5;  // 32 x 8
#pragma unroll
    for (int i = 0; i < 4; ++i)
      tile[ty + 8 * i][tx] = in[(r0 + ty + 8 * i) * C + c0 + tx];
    __syncthreads();
#pragma unroll
    for (int i = 0; i < 4; ++i)
      out[(c0 + ty + 8 * i) * R + r0 + tx] = f2bf(tile[tx][ty + 8 * i]);

  } else if (b < 2688) {  // --- cvt x_real ---
    const int i = ((b - 2176) * 256 + tid) * 4;
    f32x4 v = *(const f32x4*)&x_real[i];
    short4v s;
    s.x = f2bf(v.x); s.y = f2bf(v.y); s.z = f2bf(v.z); s.w = f2bf(v.w);
    *(short4v*)&xrbf[i] = s;

  } else {  // --- gate ---
    constexpr int BLT = 16;
    float (*tc)[64] = (float(*)[64])smem;
    const int g = b - 2688;
    const int bl0 = (g & 63) * BLT;
    const int h = (g >> 6) * 256 + tid;

#pragma unroll
    for (int e = 0; e < BLT * 64 / 256; ++e) {  // 4 elems/thread
      int f = tid + 256 * e;
      int r = f >> 6, p = f & 63;
      int bl = bl0 + r;
      int l = bl & (Lq - 1);
      tc[r][p] = x_imag[bl * Pq + p] * pos_freq[l * Pq + p];
    }
    __syncthreads();

    float acc[BLT] = {};
#pragma unroll 1
    for (int p = 0; p < Pq; p += 4) {
      float wv0 = wq[(p + 0) * Hq + h] * INV2PI, wv1 = wq[(p + 1) * Hq + h] * INV2PI;
      float wv2 = wq[(p + 2) * Hq + h] * INV2PI, wv3 = wq[(p + 3) * Hq + h] * INV2PI;
      float bv0 = bq[(p + 0) * Hq + h] * INV2PI, bv1 = bq[(p + 1) * Hq + h] * INV2PI;
      float bv2 = bq[(p + 2) * Hq + h] * INV2PI, bv3 = bq[(p + 3) * Hq + h] * INV2PI;
#pragma unroll
      for (int r = 0; r < BLT; ++r) {
        f32x4 t = *(const f32x4*)&tc[r][p];
        acc[r] += cos_rev(t.x * wv0 + bv0);
        acc[r] += cos_rev(t.y * wv1 + bv1);
        acc[r] += cos_rev(t.z * wv2 + bv2);
        acc[r] += cos_rev(t.w * wv3 + bv3);
      }
    }
#pragma unroll
    for (int r = 0; r < BLT; ++r)
      gate[(bl0 + r) * Hq + h] = f2bf(acc[r] * 0.125f);
  }
}

// ---------------------------------------------------------------------------
// Double-buffered MFMA tile core. BM=32 rows x BN=64 cols, K-steps of 32.
// 4 waves: wr = wv>>1 (16-row half), wc = wv&1 (32-col half); FN=2.
// T3-min 2-phase: stage(next buf) issued BEFORE compute(cur); one barrier
// per k-step drains vmcnt (syncthreads implies the waitcnt).
template <int NSTEPS>
DEV void mfma_core(const short* __restrict__ Arow, int lda,
                   const short* __restrict__ Brow, int ldb,
                   short* As0, short* Bs0, short* As1, short* Bs1,
                   int tid, f32x4* acc) {
  const int lane = tid & 63;
  const int wv = tid >> 6, wr = wv >> 1, wc = wv & 1;
  const int lrow = lane & 15, lk = (lane >> 4) * 8;
  const int srow = tid >> 2, sseg = (tid & 3) * 8;

  auto stage = [&](short* As, short* Bs, int k0) {
    if (tid < 128)  // A-tile: 32 rows x 32 k = 128 lanes x 16B (waves 0,1)
      gload_lds16(&Arow[srow * lda + k0 + sseg], &As[tid * 8]);
    gload_lds16(&Brow[srow * ldb + k0 + sseg], &Bs[tid * 8]);
  };
  auto compute = [&](const short* As, const short* Bs) {
    short8v a  = *(const short8v*)&As[(wr * 16 + lrow) * 32 + lk];
    short8v b0 = *(const short8v*)&Bs[(wc * 32 + lrow) * 32 + lk];
    short8v b1 = *(const short8v*)&Bs[(wc * 32 + 16 + lrow) * 32 + lk];
    acc[0] = __builtin_amdgcn_mfma_f32_16x16x32_bf16(a, b0, acc[0], 0, 0, 0);
    acc[1] = __builtin_amdgcn_mfma_f32_16x16x32_bf16(a, b1, acc[1], 0, 0, 0);
  };

  stage(As0, Bs0, 0);
  __syncthreads();
#pragma unroll 1
  for (int t = 0; t < NSTEPS; t += 2) {
    if (t + 1 < NSTEPS) stage(As1, Bs1, (t + 1) * 32);
    compute(As0, Bs0);
    __syncthreads();
    if (t + 2 < NSTEPS) stage(As0, Bs0, (t + 2) * 32);
    if (t + 1 < NSTEPS) compute(As1, Bs1);
    __syncthreads();
  }
}

// Kernel B: out(bf16) = (x_real @ W_up) * gate.  grid 32m x 32n = 1024.
__global__ __launch_bounds__(256) void fused_up(
    const short* __restrict__ xrbf, const short* __restrict__ wupT,
    const short* __restrict__ gate, short* __restrict__ outbf) {
  __shared__ __align__(16) short As[2][32 * 32];
  __shared__ __align__(16) short Bs[2][64 * 32];
  const int tid = threadIdx.x;
  const int m0 = (blockIdx.x >> 5) * 32, n0 = (blockIdx.x & 31) * 64;
  const int lane = tid & 63, wv = tid >> 6, wr = wv >> 1, wc = wv & 1;
  const int lrow = lane & 15;

  f32x4 acc[2] = {};
  mfma_core<16>(&xrbf[m0 * Dq], Dq, &wupT[n0 * Dq], Dq,
                As[0], Bs[0], As[1], Bs[1], tid, acc);

#pragma unroll
  for (int j = 0; j < 2; ++j)
#pragma unroll
    for (int r = 0; r < 4; ++r) {
      int row = m0 + wr * 16 + (lane >> 4) * 4 + r;
      int col = n0 + wc * 32 + j * 16 + lrow;
      outbf[row * Hq + col] = f2bf(acc[j][r] * bf2f(gate[row * Hq + col]));
    }
}

// Kernel C: role-split.
//   [0,256):   out_real = x_real + out @ W_down_real   (32m x 8n tiles)
//   [256,288): out_imag = x_imag + gate @ W_down_imag  (32m tiles, N=64)
__global__ __launch_bounds__(256) void fused_down(
    const short* __restrict__ outbf, const short* __restrict__ wdrT,
    const short* __restrict__ gate, const short* __restrict__ wdiT,
    const float* __restrict__ x_real, const float* __restrict__ x_imag,
    float* __restrict__ out_real, float* __restrict__ out_imag) {
  __shared__ __align__(16) short As[2][32 * 32];
  __shared__ __align__(16) short Bs[2][64 * 32];
  const int b = blockIdx.x, tid = threadIdx.x;
  const int lane = tid & 63, wv = tid >> 6, wr = wv >> 1, wc = wv & 1;
  const int lrow = lane & 15;
  f32x4 acc[2] = {};

  if (b < 256) {
    const int m0 = (b >> 3) * 32, n0 = (b & 7) * 64;
    mfma_core<64>(&outbf[m0 * Hq], Hq, &wdrT[n0 * Hq], Hq,
                  As[0], Bs[0], As[1], Bs[1], tid, acc);
#pragma unroll
    for (int j = 0; j < 2; ++j)
#pragma unroll
      for (int r = 0; r < 4; ++r) {
        int row = m0 + wr * 16 + (lane >> 4) * 4 + r;
        int col = n0 + wc * 32 + j * 16 + lrow;
        out_real[row * Dq + col] = x_real[row * Dq + col] + acc[j][r];
      }
  } else {
    const int m0 = (b - 256) * 32;
    mfma_core<64>(&gate[m0 * Hq], Hq, wdiT, Hq,
                  As[0], Bs[0], As[1], Bs[1], tid, acc);
#pragma unroll
    for (int j = 0; j < 2; ++j)
#pragma unroll
      for (int r = 0; r < 4; ++r) {
        int row = m0 + wr * 16 + (lane >> 4) * 4 + r;
        int col = wc * 32 + j * 16 + lrow;  // N = 64 = P
        out_imag[row * Pq + col] = x_imag[row * Pq + col] + acc[j][r];
      }
  }
}

// ---------------------------------------------------------------------------
extern "C" void kernel_launch(void* const* d_in, const int* in_sizes, int n_in,
                              void* d_out, int out_size, void* d_ws,
                              size_t ws_size, hipStream_t stream) {
  const float* x_real   = (const float*)d_in[0];  // (B,L,D)
  const float* x_imag   = (const float*)d_in[1];  // (B,L,P)
  const float* pos_freq = (const float*)d_in[2];  // (L,P)
  const float* W_up     = (const float*)d_in[3];  // (D,H)
  const float* wq       = (const float*)d_in[4];  // (P,H)
  const float* bq       = (const float*)d_in[5];  // (P,H)
  const float* Wdr      = (const float*)d_in[6];  // (H,D)
  const float* Wdi      = (const float*)d_in[7];  // (H,P)

  float* out_real = (float*)d_out;            // (B,L,D)
  float* out_imag = out_real + BLq * Dq;      // (B,L,P)

  char* ws = (char*)d_ws;
  short* gate_bf = (short*)ws;                      // 4 MB  [BL][H] bf16
  short* outbf   = (short*)(ws + (4u << 20));       // 4 MB  [BL][H] bf16
  short* wupT    = (short*)(ws + (8u << 20));       // 2 MB  [H][D]  bf16
  short* wdrT    = (short*)(ws + (10u << 20));      // 2 MB  [D][H]  bf16
  short* xrbf    = (short*)(ws + (12u << 20));      // 1 MB  [BL][D] bf16
  short* wdiT    = (short*)(ws + (13u << 20));      // 256KB [P][H]  bf16

  fused_prologue<<<3200, 256, 0, stream>>>(
      x_real, x_imag, pos_freq, W_up, wq, bq, Wdr, Wdi,
      wupT, wdrT, wdiT, xrbf, gate_bf);

  fused_up<<<1024, 256, 0, stream>>>(xrbf, wupT, gate_bf, outbf);

  fused_down<<<288, 256, 0, stream>>>(
      outbf, wdrT, gate_bf, wdiT, x_real, x_imag, out_real, out_imag);
}